// Round 9
// baseline (338.283 us; speedup 1.0000x reference)
//
#include <hip/hip_runtime.h>
#include <hip/hip_bf16.h>
#include <hip/hip_cooperative_groups.h>
#include <math.h>

namespace cg = cooperative_groups;

#define LDIM 4096
#define NROWS 8192
#define NOUT 512
#define CGRID 512           // cooperative grid: 2 blocks/CU, guaranteed co-resident
#define RPB (NROWS / CGRID) // 16 rows per block

static const float SQRT_HALF_F = 0.70710678118654752440f;

typedef __attribute__((ext_vector_type(8))) short short8;
typedef __attribute__((ext_vector_type(4))) float f32x4;
typedef __attribute__((ext_vector_type(8))) unsigned short u16x8;
typedef __attribute__((ext_vector_type(4))) unsigned short u16x4;
typedef __attribute__((ext_vector_type(2))) unsigned short u16x2;

// ws layout
#define AM_OFF   0ull                         // bf16 masked A: 8192*4096*2 = 67108864
#define WT_OFF   67108864ull                  // bf16 Wt (N x K): 512*4096*2 = 4194304
#define PART_OFF (WT_OFF + 4194304ull)        // double[CGRID*2]

__device__ inline unsigned short f2bf(float f) {
  union { float f; unsigned u; } v; v.f = f;
  unsigned r = (v.u + 0x7fffu + ((v.u >> 16) & 1u)) >> 16;
  return (unsigned short)r;
}

__device__ inline unsigned short mcvt(float f, float thr) {
  return f2bf((fabsf(f) > thr) ? f : 0.0f);
}

__device__ inline void async16(void* l, const void* g) {
  __builtin_amdgcn_global_load_lds((const __attribute__((address_space(1))) void*)g,
                                   (__attribute__((address_space(3))) void*)l, 16, 0, 0);
}

// ---------------- Kernel 1 (cooperative): haar stats + wcvt | thr | haar mask-write ----
// Register-resident 5-level Haar (levels 1-4 thread-local on 16 elems, level 5
// lane-pair shfl). One cooperative kernel replaces haar1/thr/haar2 chain:
// saves the thr launch + 2 inter-kernel gaps. Atomic alternatives are ruled
// out by round-1 measurement (same-line RMW ~13ns -> 8192 blocks = ~106us).
__global__ __launch_bounds__(256, 2) void haar_all_kernel(const float* __restrict__ x,
                                                          const float* __restrict__ W,
                                                          unsigned short* __restrict__ Wt,
                                                          double* __restrict__ partials,
                                                          unsigned short* __restrict__ Am) {
  __shared__ double red[8];
  __shared__ float tile[32][33];
  __shared__ float thr_s;

  const int b = blockIdx.x;
  const int t = threadIdx.x;
  const int lane = t & 63, wid = t >> 6;
  const float S = SQRT_HALF_F;

  // ---- Phase 1a: stats over 16 rows ----
  double tsa = 0.0, tsq = 0.0;
  for (int rr = 0; rr < RPB; ++rr) {
    const int row = b * RPB + rr;
    const float4* xr = (const float4*)(x + (size_t)row * LDIM) + 4 * t;
    float v[16];
#pragma unroll
    for (int k = 0; k < 4; ++k) {
      float4 q = xr[k];
      v[4 * k] = q.x; v[4 * k + 1] = q.y; v[4 * k + 2] = q.z; v[4 * k + 3] = q.w;
    }
    float a1[8], a2[4], a3[2], a4;
#pragma unroll
    for (int j = 0; j < 8; ++j) {
      float d = (v[2 * j] - v[2 * j + 1]) * S;
      a1[j] = (v[2 * j] + v[2 * j + 1]) * S;
      tsa += (double)fabsf(d); tsq += (double)d * (double)d;
    }
#pragma unroll
    for (int j = 0; j < 4; ++j) {
      float d = (a1[2 * j] - a1[2 * j + 1]) * S;
      a2[j] = (a1[2 * j] + a1[2 * j + 1]) * S;
      tsa += (double)fabsf(d); tsq += (double)d * (double)d;
    }
#pragma unroll
    for (int j = 0; j < 2; ++j) {
      float d = (a2[2 * j] - a2[2 * j + 1]) * S;
      a3[j] = (a2[2 * j] + a2[2 * j + 1]) * S;
      tsa += (double)fabsf(d); tsq += (double)d * (double)d;
    }
    {
      float d = (a3[0] - a3[1]) * S;
      a4 = (a3[0] + a3[1]) * S;
      tsa += (double)fabsf(d); tsq += (double)d * (double)d;
    }
    {
      float other = __shfl_xor(a4, 1, 64);
      if ((t & 1) == 0) {
        float d = (a4 - other) * S, ap = (a4 + other) * S;
        tsa += (double)fabsf(d) + (double)fabsf(ap);
        tsq += (double)d * (double)d + (double)ap * (double)ap;
      }
    }
  }
  // block reduction -> partials
  {
    double sa = tsa, sq = tsq;
#pragma unroll
    for (int off = 32; off > 0; off >>= 1) {
      sa += __shfl_down(sa, off, 64);
      sq += __shfl_down(sq, off, 64);
    }
    if (lane == 0) { red[wid] = sa; red[4 + wid] = sq; }
    __syncthreads();
    if (t == 0) {
      partials[2 * (size_t)b + 0] = red[0] + red[1] + red[2] + red[3];
      partials[2 * (size_t)b + 1] = red[4] + red[5] + red[6] + red[7];
    }
  }

  // ---- Phase 1b: wcvt, 4 tiles per block (2048 total) ----
  const int tx = t & 31, ty = t >> 5;
#pragma unroll
  for (int j4 = 0; j4 < 4; ++j4) {
    const int wb = b * 4 + j4;
    const int bx = wb & 15;        // n tile (16)
    const int by = wb >> 4;        // k tile (128)
    __syncthreads();
#pragma unroll
    for (int j = 0; j < 4; ++j)
      tile[ty + j * 8][tx] = W[(size_t)(by * 32 + ty + j * 8) * NOUT + bx * 32 + tx];
    __syncthreads();
#pragma unroll
    for (int j = 0; j < 4; ++j)
      Wt[(size_t)(bx * 32 + ty + j * 8) * LDIM + by * 32 + tx] = f2bf(tile[tx][ty + j * 8]);
  }

  // ---- grid-wide sync: all partials visible ----
  cg::this_grid().sync();

  // ---- Phase 2: every block reduces partials -> thr ----
  {
    double sa = 0.0, sq = 0.0;
    for (int i = t; i < CGRID; i += 256) {
      sa += partials[2 * i + 0];
      sq += partials[2 * i + 1];
    }
#pragma unroll
    for (int off = 32; off > 0; off >>= 1) {
      sa += __shfl_down(sa, off, 64);
      sq += __shfl_down(sq, off, 64);
    }
    if (lane == 0) { red[wid] = sa; red[4 + wid] = sq; }
    __syncthreads();
    if (t == 0) {
      double s = red[0] + red[1] + red[2] + red[3];
      double q = red[4] + red[5] + red[6] + red[7];
      const double n = (double)NROWS * (double)LDIM;
      double mean = s / n;
      double var = (q - s * s / n) / (n - 1.0);
      thr_s = (float)(mean + sqrt(var));
    }
    __syncthreads();
  }
  const float thr = thr_s;

  // ---- Phase 3: recompute DWT, mask, write bf16 Am (x re-read is LLC-hot) ----
  for (int rr = 0; rr < RPB; ++rr) {
    const int row = b * RPB + rr;
    const float4* xr = (const float4*)(x + (size_t)row * LDIM) + 4 * t;
    float v[16];
#pragma unroll
    for (int k = 0; k < 4; ++k) {
      float4 q = xr[k];
      v[4 * k] = q.x; v[4 * k + 1] = q.y; v[4 * k + 2] = q.z; v[4 * k + 3] = q.w;
    }
    unsigned short* orow = Am + (size_t)row * LDIM;
    float a1[8], a2[4], a3[2], a4;

    u16x8 d1;
#pragma unroll
    for (int j = 0; j < 8; ++j) {
      float d = (v[2 * j] - v[2 * j + 1]) * S;
      a1[j] = (v[2 * j] + v[2 * j + 1]) * S;
      d1[j] = mcvt(d, thr);
    }
    *(u16x8*)(orow + 2048 + 8 * t) = d1;

    u16x4 d2;
#pragma unroll
    for (int j = 0; j < 4; ++j) {
      float d = (a1[2 * j] - a1[2 * j + 1]) * S;
      a2[j] = (a1[2 * j] + a1[2 * j + 1]) * S;
      d2[j] = mcvt(d, thr);
    }
    *(u16x4*)(orow + 1024 + 4 * t) = d2;

    u16x2 d3;
#pragma unroll
    for (int j = 0; j < 2; ++j) {
      float d = (a2[2 * j] - a2[2 * j + 1]) * S;
      a3[j] = (a2[2 * j] + a2[2 * j + 1]) * S;
      d3[j] = mcvt(d, thr);
    }
    *(u16x2*)(orow + 512 + 2 * t) = d3;

    {
      float d = (a3[0] - a3[1]) * S;
      a4 = (a3[0] + a3[1]) * S;
      orow[256 + t] = mcvt(d, thr);
    }
    {
      float other = __shfl_xor(a4, 1, 64);
      if ((t & 1) == 0) {
        float d = (a4 - other) * S, ap = (a4 + other) * S;
        orow[128 + t / 2] = mcvt(d, thr);
        orow[t / 2] = mcvt(ap, thr);
      }
    }
  }
}

// ---------------- Kernel 2: bf16 MFMA GEMM + ReLU (round-7 version, verbatim) ----
// Tile 64m x 64n, BK=128, 256 threads (4 waves, wave tile 32x32, 16 MFMA/iter),
// grid 1024 = 4 blocks/CU. Round-8's barrier-free restructure REGRESSED
// (57 vs 40 us: 1-step pipeline depth < load latency, 2 blocks/CU) — this
// 2-barrier form sits at the ~860 TF m97-structure plateau, which is the
// practical HIP-level ceiling (m99-m141; fp8 inadmissible numerically).
__global__ __launch_bounds__(256, 4) void gemm_kernel(const unsigned short* __restrict__ Am,
                                                      const unsigned short* __restrict__ Wt,
                                                      float* __restrict__ out) {
  __shared__ __align__(16) unsigned short As[64 * 128];  // 16 KB
  __shared__ __align__(16) unsigned short Bs[64 * 128];  // 16 KB

  const int tid = threadIdx.x;
  const int lane = tid & 63, w = tid >> 6;      // 4 waves
  const int quad = lane >> 4, l15 = lane & 15;
  const int wm = w >> 1, wn = w & 1;            // 2 x 2 wave grid

  const int id = blockIdx.x;
  const int xcd = id & 7, slot = id >> 3;       // slot 0..127
  const int nblk = slot & 7;                    // 8 n-blocks
  const int mblk = (slot >> 3) * 8 + xcd;       // 128 m-strips
  const int n0 = nblk * 64, m0 = mblk * 64;

  f32x4 acc[2][2] = {};

  const int rl = lane >> 3;            // row within 8-row group
  const int cg_ = (lane & 7) ^ rl;     // swizzled source chunk
  const unsigned short* AgBase = Am + (size_t)(m0 + rl) * LDIM + cg_ * 8;
  const unsigned short* BgBase = Wt + (size_t)(n0 + rl) * LDIM + cg_ * 8;

  for (int k0 = 0; k0 < LDIM; k0 += 128) {
#pragma unroll
    for (int j = 0; j < 2; ++j) {
      const int g = w * 2 + j;
      const size_t gro = (size_t)(g * 8) * LDIM + k0;
      async16(&As[g * 1024], AgBase + gro);                  // k-chunks 0..7
      async16(&As[g * 1024 + 512], AgBase + gro + 64);       // k-chunks 8..15
      async16(&Bs[g * 1024], BgBase + gro);
      async16(&Bs[g * 1024 + 512], BgBase + gro + 64);
    }
    __syncthreads();

    short8 af[2][4], bf[2][4];
#pragma unroll
    for (int mi = 0; mi < 2; ++mi) {
      const int row = wm * 32 + mi * 16 + l15;
      const int rg = row >> 3, ro = row & 7;
#pragma unroll
      for (int ks = 0; ks < 4; ++ks) {
        const int c = ks * 4 + quad;
        af[mi][ks] = *(const short8*)&As[rg * 1024 + (c & 8) * 64 + ro * 64 + ((c ^ ro) & 7) * 8];
      }
    }
#pragma unroll
    for (int ni = 0; ni < 2; ++ni) {
      const int row = wn * 32 + ni * 16 + l15;
      const int rg = row >> 3, ro = row & 7;
#pragma unroll
      for (int ks = 0; ks < 4; ++ks) {
        const int c = ks * 4 + quad;
        bf[ni][ks] = *(const short8*)&Bs[rg * 1024 + (c & 8) * 64 + ro * 64 + ((c ^ ro) & 7) * 8];
      }
    }
#pragma unroll
    for (int ks = 0; ks < 4; ++ks)
#pragma unroll
      for (int mi = 0; mi < 2; ++mi)
#pragma unroll
        for (int ni = 0; ni < 2; ++ni)
          acc[mi][ni] = __builtin_amdgcn_mfma_f32_16x16x32_bf16(af[mi][ks], bf[ni][ks],
                                                                acc[mi][ni], 0, 0, 0);
    __syncthreads();
  }

  // C/D layout: col = lane&15, row = quad*4 + reg (verified rounds 1-7)
#pragma unroll
  for (int mi = 0; mi < 2; ++mi) {
#pragma unroll
    for (int ni = 0; ni < 2; ++ni) {
      const int r0 = m0 + wm * 32 + mi * 16 + quad * 4;
      const int c = n0 + wn * 32 + ni * 16 + l15;
#pragma unroll
      for (int r = 0; r < 4; ++r)
        out[(size_t)(r0 + r) * NOUT + c] = fmaxf(acc[mi][ni][r], 0.0f);
    }
  }
}

extern "C" void kernel_launch(void* const* d_in, const int* in_sizes, int n_in,
                              void* d_out, int out_size, void* d_ws, size_t ws_size,
                              hipStream_t stream) {
  const float* x = (const float*)d_in[0];
  const float* W = (const float*)d_in[1];
  float* out = (float*)d_out;

  char* ws = (char*)d_ws;
  unsigned short* Am = (unsigned short*)(ws + AM_OFF);
  unsigned short* Wt = (unsigned short*)(ws + WT_OFF);
  double* partials = (double*)(ws + PART_OFF);

  void* args[] = {(void*)&x, (void*)&W, (void*)&Wt, (void*)&partials, (void*)&Am};
  hipLaunchCooperativeKernel((const void*)haar_all_kernel, dim3(CGRID), dim3(256),
                             args, 0, stream);
  gemm_kernel<<<1024, 256, 0, stream>>>(Am, Wt, out);
}

// Round 10
// 269.825 us; speedup vs baseline: 1.2537x; 1.2537x over previous
//
#include <hip/hip_runtime.h>
#include <hip/hip_bf16.h>
#include <math.h>

#define LDIM 4096
#define NROWS 8192
#define NOUT 512

static const float SQRT_HALF_F = 0.70710678118654752440f;

typedef __attribute__((ext_vector_type(8))) short short8;
typedef __attribute__((ext_vector_type(4))) float f32x4;
typedef __attribute__((ext_vector_type(8))) unsigned short u16x8;
typedef __attribute__((ext_vector_type(4))) unsigned short u16x4;
typedef __attribute__((ext_vector_type(2))) unsigned short u16x2;

// ws layout
#define AM_OFF   0ull                         // bf16 masked A: 8192*4096*2 = 67108864
#define WT_OFF   67108864ull                  // bf16 Wt (N x K): 512*4096*2 = 4194304
#define PART_OFF (WT_OFF + 4194304ull)        // double[8192*2] partials
#define THR_OFF  (PART_OFF + 131072ull)       // float[1]

// SESSION NOTE (rounds 8-9): two structural experiments regressed and are
// reverted here. (a) Barrier-free per-wave-k-slice GEMM: 57 vs 40 us —
// 1-step pipeline < load latency, and 64 KB LDS halved occupancy. (b)
// Cooperative-kernel fusion of the haar chain: 130 vs ~60 us — co-resident
// grid (512 = 2 blocks/CU) starves memory parallelism (22% occupancy,
// 1.6 TB/s), and scaling the grid is blocked by grid.sync's per-block
// same-line RMW (~13 ns x blocks). This file is the round-5 measured best
// (268.0 us): haar1+wcvt / thr / haar2 / 2-barrier MFMA GEMM at the ~860 TF
// m97-structure plateau.

__device__ inline unsigned short f2bf(float f) {
  union { float f; unsigned u; } v; v.f = f;
  unsigned r = (v.u + 0x7fffu + ((v.u >> 16) & 1u)) >> 16;
  return (unsigned short)r;
}

__device__ inline unsigned short mcvt(float f, float thr) {
  return f2bf((fabsf(f) > thr) ? f : 0.0f);
}

__device__ inline void async16(void* l, const void* g) {
  __builtin_amdgcn_global_load_lds((const __attribute__((address_space(1))) void*)g,
                                   (__attribute__((address_space(3))) void*)l, 16, 0, 0);
}

// ---------------- Kernel 1: Haar stats (blocks 0..8191) + W convert (tail) ----
__global__ __launch_bounds__(256) void haar1_kernel(const float* __restrict__ x,
                                                    double* __restrict__ partials,
                                                    const float* __restrict__ W,
                                                    unsigned short* __restrict__ Wt) {
  if (blockIdx.x >= NROWS) {
    // ---- fused wcvt: W (K x N fp32) -> Wt (N x K bf16) ----
    __shared__ float tile[32][33];
    const int wb = blockIdx.x - NROWS;
    const int bx = wb & 15;        // n tile (16)
    const int by = wb >> 4;        // k tile (128)
    const int tx = threadIdx.x & 31, ty = threadIdx.x >> 5;
#pragma unroll
    for (int j = 0; j < 4; ++j)
      tile[ty + j * 8][tx] = W[(size_t)(by * 32 + ty + j * 8) * NOUT + bx * 32 + tx];
    __syncthreads();
#pragma unroll
    for (int j = 0; j < 4; ++j)
      Wt[(size_t)(bx * 32 + ty + j * 8) * LDIM + by * 32 + tx] = f2bf(tile[tx][ty + j * 8]);
    return;
  }

  __shared__ double red[8];
  const int row = blockIdx.x;
  const int t = threadIdx.x;
  const float S = SQRT_HALF_F;

  const float4* xr = (const float4*)(x + (size_t)row * LDIM) + 4 * t;
  float v[16];
#pragma unroll
  for (int k = 0; k < 4; ++k) {
    float4 q = xr[k];
    v[4 * k] = q.x; v[4 * k + 1] = q.y; v[4 * k + 2] = q.z; v[4 * k + 3] = q.w;
  }

  double sa = 0.0, sq = 0.0;
  float a1[8], a2[4], a3[2], a4;
#pragma unroll
  for (int j = 0; j < 8; ++j) {
    float d = (v[2 * j] - v[2 * j + 1]) * S;
    a1[j] = (v[2 * j] + v[2 * j + 1]) * S;
    sa += (double)fabsf(d); sq += (double)d * (double)d;
  }
#pragma unroll
  for (int j = 0; j < 4; ++j) {
    float d = (a1[2 * j] - a1[2 * j + 1]) * S;
    a2[j] = (a1[2 * j] + a1[2 * j + 1]) * S;
    sa += (double)fabsf(d); sq += (double)d * (double)d;
  }
#pragma unroll
  for (int j = 0; j < 2; ++j) {
    float d = (a2[2 * j] - a2[2 * j + 1]) * S;
    a3[j] = (a2[2 * j] + a2[2 * j + 1]) * S;
    sa += (double)fabsf(d); sq += (double)d * (double)d;
  }
  {
    float d = (a3[0] - a3[1]) * S;
    a4 = (a3[0] + a3[1]) * S;
    sa += (double)fabsf(d); sq += (double)d * (double)d;
  }
  {
    float other = __shfl_xor(a4, 1, 64);
    if ((t & 1) == 0) {
      float d = (a4 - other) * S, ap = (a4 + other) * S;
      sa += (double)fabsf(d) + (double)fabsf(ap);
      sq += (double)d * (double)d + (double)ap * (double)ap;
    }
  }

  const int lane = t & 63, wid = t >> 6;
#pragma unroll
  for (int off = 32; off > 0; off >>= 1) {
    sa += __shfl_down(sa, off, 64);
    sq += __shfl_down(sq, off, 64);
  }
  if (lane == 0) { red[wid] = sa; red[4 + wid] = sq; }
  __syncthreads();
  if (t == 0) {
    partials[2 * (size_t)row + 0] = red[0] + red[1] + red[2] + red[3];
    partials[2 * (size_t)row + 1] = red[4] + red[5] + red[6] + red[7];
  }
}

// ---------------- Kernel 2: reduce partials -> threshold ----------------
__global__ __launch_bounds__(1024) void thr_kernel(const double* __restrict__ partials,
                                                   float* __restrict__ thr) {
  __shared__ double red[32];
  const int tid = threadIdx.x;
  double sa = 0.0, sq = 0.0;
#pragma unroll
  for (int k = 0; k < NROWS / 1024; ++k) {
    int i = tid + k * 1024;
    sa += partials[2 * i + 0];
    sq += partials[2 * i + 1];
  }
  const int lane = tid & 63, wid = tid >> 6;
#pragma unroll
  for (int off = 32; off > 0; off >>= 1) {
    sa += __shfl_down(sa, off, 64);
    sq += __shfl_down(sq, off, 64);
  }
  if (lane == 0) { red[wid] = sa; red[16 + wid] = sq; }
  __syncthreads();
  if (tid == 0) {
    double s = 0.0, q = 0.0;
#pragma unroll
    for (int i = 0; i < 16; ++i) { s += red[i]; q += red[16 + i]; }
    const double n = (double)NROWS * (double)LDIM;
    double mean = s / n;
    double var = (q - s * s / n) / (n - 1.0);
    *thr = (float)(mean + sqrt(var));
  }
}

// ---------------- Kernel 3: Haar recompute + mask + bf16 write ----------------
__global__ __launch_bounds__(256) void haar2_kernel(const float* __restrict__ x,
                                                    const float* __restrict__ thrp,
                                                    unsigned short* __restrict__ Am) {
  const float thr = *thrp;
  const int row = blockIdx.x;
  const int t = threadIdx.x;
  const float S = SQRT_HALF_F;

  const float4* xr = (const float4*)(x + (size_t)row * LDIM) + 4 * t;
  float v[16];
#pragma unroll
  for (int k = 0; k < 4; ++k) {
    float4 q = xr[k];
    v[4 * k] = q.x; v[4 * k + 1] = q.y; v[4 * k + 2] = q.z; v[4 * k + 3] = q.w;
  }

  unsigned short* orow = Am + (size_t)row * LDIM;
  float a1[8], a2[4], a3[2], a4;

  u16x8 d1;
#pragma unroll
  for (int j = 0; j < 8; ++j) {
    float d = (v[2 * j] - v[2 * j + 1]) * S;
    a1[j] = (v[2 * j] + v[2 * j + 1]) * S;
    d1[j] = mcvt(d, thr);
  }
  *(u16x8*)(orow + 2048 + 8 * t) = d1;

  u16x4 d2;
#pragma unroll
  for (int j = 0; j < 4; ++j) {
    float d = (a1[2 * j] - a1[2 * j + 1]) * S;
    a2[j] = (a1[2 * j] + a1[2 * j + 1]) * S;
    d2[j] = mcvt(d, thr);
  }
  *(u16x4*)(orow + 1024 + 4 * t) = d2;

  u16x2 d3;
#pragma unroll
  for (int j = 0; j < 2; ++j) {
    float d = (a2[2 * j] - a2[2 * j + 1]) * S;
    a3[j] = (a2[2 * j] + a2[2 * j + 1]) * S;
    d3[j] = mcvt(d, thr);
  }
  *(u16x2*)(orow + 512 + 2 * t) = d3;

  {
    float d = (a3[0] - a3[1]) * S;
    a4 = (a3[0] + a3[1]) * S;
    orow[256 + t] = mcvt(d, thr);
  }
  {
    float other = __shfl_xor(a4, 1, 64);
    if ((t & 1) == 0) {
      float d = (a4 - other) * S, ap = (a4 + other) * S;
      orow[128 + t / 2] = mcvt(d, thr);
      orow[t / 2] = mcvt(ap, thr);
    }
  }
}

// ---------------- Kernel 4: bf16 MFMA GEMM + ReLU, 512 threads ----------------
// Round-5 measured-best config. Tile 128m x 64n, BK=64, 8 waves/block (wave
// tile 32x32), grid 512: xcd = id&7, mblk = (slot>>3)*8 + xcd -> all 8
// n-blocks of an A-strip co-run on one XCD (A strip L2-resident; round-2's
// naive grid refetched A 8x = 286 MB). LDS XOR-8 chunk swizzle via DMA
// source address -> 2-way bank aliasing only (round-2 unswizzled: 6.29M
// conflicts). Sits at the ~860 TF m97-structure plateau — further gain
// needs restructured K-loop (round-8 attempt regressed; hand-asm territory).
__global__ __launch_bounds__(512) void gemm_kernel(const unsigned short* __restrict__ Am,
                                                   const unsigned short* __restrict__ Wt,
                                                   float* __restrict__ out) {
  __shared__ __align__(16) unsigned short As[128 * 64];  // 16 KB
  __shared__ __align__(16) unsigned short Bs[64 * 64];   //  8 KB

  const int tid = threadIdx.x;
  const int lane = tid & 63, w = tid >> 6;      // 8 waves
  const int quad = lane >> 4, l15 = lane & 15;
  const int wm = w >> 1, wn = w & 1;            // 4 x 2 wave grid

  const int id = blockIdx.x;
  const int xcd = id & 7, slot = id >> 3;
  const int nblk = slot & 7;
  const int mblk = (slot >> 3) * 8 + xcd;
  const int n0 = nblk * 64, m0 = mblk * 128;

  f32x4 acc[2][2] = {};

  const int rl = lane >> 3;            // row within an 8-row DMA group
  const int cg = (lane & 7) ^ rl;      // XOR-swizzled source chunk index
  const unsigned short* AgBase = Am + (size_t)(m0 + rl) * LDIM + cg * 8;
  const unsigned short* BgBase = Wt + (size_t)(n0 + rl) * LDIM + cg * 8;

  for (int k0 = 0; k0 < LDIM; k0 += 64) {
    // A: 128 rows, wave w covers rows (w*2+j)*8..+8, j=0,1
#pragma unroll
    for (int j = 0; j < 2; ++j)
      async16(&As[(w * 2 + j) * 512], AgBase + (size_t)((w * 2 + j) * 8) * LDIM + k0);
    // B: 64 rows, wave w covers rows w*8..+8
    async16(&Bs[w * 512], BgBase + (size_t)(w * 8) * LDIM + k0);
    __syncthreads();

    short8 af[2][2], bf[2][2];
#pragma unroll
    for (int mi = 0; mi < 2; ++mi) {
      const int row = wm * 32 + mi * 16 + l15;
#pragma unroll
      for (int ks = 0; ks < 2; ++ks)
        af[mi][ks] = *(const short8*)&As[row * 64 + ((ks * 4 + quad) ^ (row & 7)) * 8];
    }
#pragma unroll
    for (int ni = 0; ni < 2; ++ni) {
      const int row = wn * 32 + ni * 16 + l15;
#pragma unroll
      for (int ks = 0; ks < 2; ++ks)
        bf[ni][ks] = *(const short8*)&Bs[row * 64 + ((ks * 4 + quad) ^ (row & 7)) * 8];
    }
#pragma unroll
    for (int ks = 0; ks < 2; ++ks)
#pragma unroll
      for (int mi = 0; mi < 2; ++mi)
#pragma unroll
        for (int ni = 0; ni < 2; ++ni)
          acc[mi][ni] = __builtin_amdgcn_mfma_f32_16x16x32_bf16(af[mi][ks], bf[ni][ks],
                                                                acc[mi][ni], 0, 0, 0);
    __syncthreads();
  }

  // C/D layout: col = lane&15, row = quad*4 + reg (verified rounds 1-7)
#pragma unroll
  for (int mi = 0; mi < 2; ++mi) {
#pragma unroll
    for (int ni = 0; ni < 2; ++ni) {
      const int r0 = m0 + wm * 32 + mi * 16 + quad * 4;
      const int c = n0 + wn * 32 + ni * 16 + l15;
#pragma unroll
      for (int r = 0; r < 4; ++r)
        out[(size_t)(r0 + r) * NOUT + c] = fmaxf(acc[mi][ni][r], 0.0f);
    }
  }
}

extern "C" void kernel_launch(void* const* d_in, const int* in_sizes, int n_in,
                              void* d_out, int out_size, void* d_ws, size_t ws_size,
                              hipStream_t stream) {
  const float* x = (const float*)d_in[0];
  const float* W = (const float*)d_in[1];
  float* out = (float*)d_out;

  char* ws = (char*)d_ws;
  unsigned short* Am = (unsigned short*)(ws + AM_OFF);
  unsigned short* Wt = (unsigned short*)(ws + WT_OFF);
  double* partials = (double*)(ws + PART_OFF);
  float* thr = (float*)(ws + THR_OFF);

  haar1_kernel<<<NROWS + 2048, 256, 0, stream>>>(x, partials, W, Wt);
  thr_kernel<<<1, 1024, 0, stream>>>(partials, thr);
  haar2_kernel<<<NROWS, 256, 0, stream>>>(x, thr, Am);
  gemm_kernel<<<512, 512, 0, stream>>>(Am, Wt, out);
}